// Round 1
// 741.186 us; speedup vs baseline: 1.0856x; 1.0856x over previous
//
#include <hip/hip_runtime.h>
#include <hip/hip_bf16.h>
#include <math.h>

#define B_ 64
#define L_ 2048
#define C_ 512
#define R_ 64
#define TL 16

#define BM 128     // c-tile per block in k_hlow (4 waves x 32 c)
#define BK 32      // l-chunk (one MFMA K)
#define LDK 36     // padded LDS row length in floats
#define NSL 8      // L-slices in k_hlow (occupancy: 2048 blocks)
#define LSL (L_ / NSL)

typedef __attribute__((ext_vector_type(8))) short bf16x8;  // 8 bf16 (4 VGPRs)
typedef __attribute__((ext_vector_type(4))) float f32x4;   // MFMA acc

static __device__ __forceinline__ unsigned pkbf(float a, float b) {
    __hip_bfloat162 t = __float22bfloat162_rn(make_float2(a, b));
    union { __hip_bfloat162 h; unsigned u; } cv;
    cv.h = t;
    return cv.u;
}

// ---------------------------------------------------------------------------
// Cast Wd (R,L) and Wu (L,R) fp32 -> bf16, same layouts. Both row-major
// layouts are exactly what the MFMA fragments want (contiguous K=inner dim).
// ---------------------------------------------------------------------------
__global__ void k_cast(const float* __restrict__ Wd,
                       const float* __restrict__ Wu,
                       __hip_bfloat16* __restrict__ Wt,
                       __hip_bfloat16* __restrict__ Wub) {
    int i = blockIdx.x * 256 + threadIdx.x;   // grid = 2*R_*L_/256
    if (i < R_ * L_) Wt[i] = __float2bfloat16(Wd[i]);
    else             Wub[i - R_ * L_] = __float2bfloat16(Wu[i - R_ * L_]);
}

// ---------------------------------------------------------------------------
// Kernel A (MFMA): hl[b][c][r] += sum_l x[b][l][c] * Wd[r][l]   ((B,C,R) now!)
// Grid (C_/BM, NSL=8, B_) = 2048 blocks -> ~5 waves/SIMD (was 2).
// K-slice partials combined via fp32 atomicAdd into zero-initialized hl.
// New (B,C,R) layout: atomics per instr land in 64B segments (16 consecutive
// r per quad) instead of 16 lines 2KB apart.
// ---------------------------------------------------------------------------
__global__ __launch_bounds__(256) void k_hlow_mfma(
        const float* __restrict__ x,
        const __hip_bfloat16* __restrict__ Wt,
        float* __restrict__ hl) {
    __shared__ float xs[BM][LDK];            // 18432 B

    const int tid  = threadIdx.x;
    const int lane = tid & 63;
    const int wv   = tid >> 6;               // 0..3
    const int quad = lane >> 4;              // 0..3 -> k-offset quad*8
    const int mrow = lane & 15;

    const int c0     = blockIdx.x * BM;
    const int l_base = blockIdx.y * LSL;
    const int b      = blockIdx.z;

    const int cs = tid & 127;
    const int lh = (tid >> 7) * 16;          // 0 or 16

    f32x4 acc[2][4];
#pragma unroll
    for (int mt = 0; mt < 2; ++mt)
#pragma unroll
        for (int nt = 0; nt < 4; ++nt)
#pragma unroll
            for (int e = 0; e < 4; ++e) acc[mt][nt][e] = 0.f;

    const float* xptr = x + ((size_t)b * L_ + l_base + lh) * C_ + c0 + cs;
    const __hip_bfloat16* wbase = Wt + l_base + quad * 8;

    for (int kc = 0; kc < LSL; kc += BK) {
        float v[16];
#pragma unroll
        for (int i = 0; i < 16; ++i) v[i] = xptr[(size_t)(kc + i) * C_];

        bf16x8 bfr[4];
#pragma unroll
        for (int nt = 0; nt < 4; ++nt)
            bfr[nt] = *reinterpret_cast<const bf16x8*>(
                wbase + (size_t)(nt * 16 + mrow) * L_ + kc);

        __syncthreads();
#pragma unroll
        for (int i = 0; i < 16; i += 4)
            *reinterpret_cast<float4*>(&xs[cs][lh + i]) =
                make_float4(v[i], v[i + 1], v[i + 2], v[i + 3]);
        __syncthreads();

#pragma unroll
        for (int mt = 0; mt < 2; ++mt) {
            const float* ap = &xs[wv * 32 + mt * 16 + mrow][quad * 8];
            float4 lo = *reinterpret_cast<const float4*>(ap);
            float4 hi = *reinterpret_cast<const float4*>(ap + 4);
            union { bf16x8 v8; unsigned u[4]; } af;
            af.u[0] = pkbf(lo.x, lo.y);
            af.u[1] = pkbf(lo.z, lo.w);
            af.u[2] = pkbf(hi.x, hi.y);
            af.u[3] = pkbf(hi.z, hi.w);
#pragma unroll
            for (int nt = 0; nt < 4; ++nt)
                acc[mt][nt] = __builtin_amdgcn_mfma_f32_16x16x32_bf16(
                    af.v8, bfr[nt], acc[mt][nt], 0, 0, 0);
        }
    }

    // C/D: col(n=r)=lane&15, row(m=c)=quad*4+e  -> hl[b][c][r]
#pragma unroll
    for (int mt = 0; mt < 2; ++mt)
#pragma unroll
        for (int nt = 0; nt < 4; ++nt) {
            const int rg = nt * 16 + mrow;
            const int cg = c0 + wv * 32 + mt * 16 + quad * 4;
#pragma unroll
            for (int e = 0; e < 4; ++e)
                atomicAdd(&hl[((size_t)b * C_ + cg + e) * R_ + rg],
                          acc[mt][nt][e]);
        }
}

// ---------------------------------------------------------------------------
// Kernel B: per (b,c): Q/K norms, P = (q/|q|)*sigmoid(g+bg), G += (k/|k|)*v.
// Thread = (c, s-octet): 256 thr = 32 c x 8 s-groups; grid (C/32, B) = 1024
// blocks = 4 waves/SIMD (was 2). q/k/v/g kept in VGPRs -> no pass-2 recompute
// (6144 -> 2048 FMA/thread). h consumed in 16-r chunks to cap VGPR.
// P stored fp32 (B,C,R): r-contiguous = k_out's MFMA B-fragment layout.
// ---------------------------------------------------------------------------
__global__ __launch_bounds__(256) void k_qkvg(
        const float* __restrict__ hl,
        const float* __restrict__ bd,
        const float* __restrict__ Wq,
        const float* __restrict__ Wk,
        const float* __restrict__ Wv,
        const float* __restrict__ Wg,
        const float* __restrict__ bg,
        float* __restrict__ P,
        float* __restrict__ G) {
    const int tid = threadIdx.x;
    const int ci  = tid & 31;            // c within tile
    const int sg  = tid >> 5;            // 0..7 -> s in [8sg, 8sg+8)
    const int wv  = tid >> 6;            // 0..3
    const int c   = blockIdx.x * 32 + ci;
    const int b   = blockIdx.y;
    const int s0  = sg * 8;
    const float* hrow = hl + ((size_t)b * C_ + c) * R_;

    float q[8], k[8], v[8], g[8];
#pragma unroll
    for (int i = 0; i < 8; ++i) { q[i] = 0.f; k[i] = 0.f; v[i] = 0.f; g[i] = 0.f; }

#pragma unroll 1
    for (int jc = 0; jc < 4; ++jc) {     // r-chunks of 16
        float hc[16];
        const float4* h4 = reinterpret_cast<const float4*>(hrow + jc * 16);
        const float4* b4 = reinterpret_cast<const float4*>(bd + jc * 16);
#pragma unroll
        for (int t = 0; t < 4; ++t) {
            float4 hv = h4[t], bv = b4[t];
            hc[4 * t + 0] = hv.x + bv.x;
            hc[4 * t + 1] = hv.y + bv.y;
            hc[4 * t + 2] = hv.z + bv.z;
            hc[4 * t + 3] = hv.w + bv.w;
        }
#pragma unroll
        for (int i = 0; i < 8; ++i) {
            const float4* wq4 = reinterpret_cast<const float4*>(Wq + (size_t)(s0 + i) * R_ + jc * 16);
            const float4* wk4 = reinterpret_cast<const float4*>(Wk + (size_t)(s0 + i) * R_ + jc * 16);
            const float4* wv4 = reinterpret_cast<const float4*>(Wv + (size_t)(s0 + i) * R_ + jc * 16);
            const float4* wg4 = reinterpret_cast<const float4*>(Wg + (size_t)(s0 + i) * R_ + jc * 16);
#pragma unroll
            for (int t = 0; t < 4; ++t) {
                float4 a = wq4[t], d = wk4[t], e2 = wv4[t], f = wg4[t];
                float h0 = hc[4 * t], h1 = hc[4 * t + 1], h2 = hc[4 * t + 2], h3 = hc[4 * t + 3];
                q[i] += h0 * a.x  + h1 * a.y  + h2 * a.z  + h3 * a.w;
                k[i] += h0 * d.x  + h1 * d.y  + h2 * d.z  + h3 * d.w;
                v[i] += h0 * e2.x + h1 * e2.y + h2 * e2.z + h3 * e2.w;
                g[i] += h0 * f.x  + h1 * f.y  + h2 * f.z  + h3 * f.w;
            }
        }
    }

    // norm sums over s: 8 local + pair-sg via xor32 + 4 waves via LDS
    float sq = 0.f, sk = 0.f;
#pragma unroll
    for (int i = 0; i < 8; ++i) { sq += q[i] * q[i]; sk += k[i] * k[i]; }
    sq += __shfl_xor(sq, 32, 64);
    sk += __shfl_xor(sk, 32, 64);
    __shared__ float rqs[4][32], rks[4][32];
    if ((tid & 32) == 0) { rqs[wv][ci] = sq; rks[wv][ci] = sk; }
    __syncthreads();
    sq = rqs[0][ci] + rqs[1][ci] + rqs[2][ci] + rqs[3][ci];
    sk = rks[0][ci] + rks[1][ci] + rks[2][ci] + rks[3][ci];
    const float inq = 1.f / fmaxf(sqrtf(sq), 1e-12f);
    const float ink = 1.f / fmaxf(sqrtf(sk), 1e-12f);

    float pv[8], kv[8];
#pragma unroll
    for (int i = 0; i < 8; ++i) {
        const float gate = 1.f / (1.f + expf(-(g[i] + bg[s0 + i])));
        pv[i] = q[i] * inq * gate;
        kv[i] = (k[i] * ink) * v[i];
    }
    float* prow = P + ((size_t)b * C_ + c) * R_ + s0;
    *reinterpret_cast<float4*>(prow)     = make_float4(pv[0], pv[1], pv[2], pv[3]);
    *reinterpret_cast<float4*>(prow + 4) = make_float4(pv[4], pv[5], pv[6], pv[7]);

    // G: reduce kv over the 32 c-lanes of this sg half-wave, then atomic
#pragma unroll
    for (int off = 1; off < 32; off <<= 1)
#pragma unroll
        for (int i = 0; i < 8; ++i) kv[i] += __shfl_xor(kv[i], off, 64);
    if (ci == 0)
#pragma unroll
        for (int i = 0; i < 8; ++i) atomicAdd(&G[b * R_ + s0 + i], kv[i]);
}

// ---------------------------------------------------------------------------
// Kernel C (MFMA): out = LN_c( x + alpha*((P.G) @ Wu^T + bu) )*gamma + beta
// Block = 16 l x 512 c, 512 thr = 8 waves; wave wv owns c in [64wv, 64wv+64).
// MFMA 16x16x32: A = Wu bf16 (m=l, k=r), B = P[c][r]*G[r] bf16 (n=c, k=r),
// fp32 accum. D: col(lane&15)=c, row(quad*4+e)=l. 8 MFMA/wave replaces 1024
// scalar FMA/thread.
// ---------------------------------------------------------------------------
__global__ __launch_bounds__(512) void k_out(const float* __restrict__ x,
                                             const float* __restrict__ P,
                                             const float* __restrict__ G,
                                             const __hip_bfloat16* __restrict__ Wub,
                                             const float* __restrict__ bu,
                                             const float* __restrict__ gamma,
                                             const float* __restrict__ beta,
                                             const float* __restrict__ alpha_p,
                                             float* __restrict__ out) {
    const int tid  = threadIdx.x;
    const int lane = tid & 63;
    const int wv   = tid >> 6;        // 0..7
    const int n16  = lane & 15;
    const int quad = lane >> 4;
    const int b    = blockIdx.y;
    const int l0   = blockIdx.x * TL;
    const float alpha = alpha_p[0];

    // A-frags: Wu row (l0+n16), k = ks*32 + quad*8 + j
    const __hip_bfloat16* wrow = Wub + (size_t)(l0 + n16) * R_ + quad * 8;
    const bf16x8 af0 = *reinterpret_cast<const bf16x8*>(wrow);
    const bf16x8 af1 = *reinterpret_cast<const bf16x8*>(wrow + 32);

    // G frags aligned with B-frag k mapping
    const float* gp = G + b * R_ + quad * 8;
    const float4 ga0 = *reinterpret_cast<const float4*>(gp);
    const float4 ga1 = *reinterpret_cast<const float4*>(gp + 4);
    const float4 gb0 = *reinterpret_cast<const float4*>(gp + 32);
    const float4 gb1 = *reinterpret_cast<const float4*>(gp + 36);

    f32x4 acc[4];
#pragma unroll
    for (int nt = 0; nt < 4; ++nt)
#pragma unroll
        for (int e = 0; e < 4; ++e) acc[nt][e] = 0.f;

    const int cb = wv * 64;
#pragma unroll
    for (int nt = 0; nt < 4; ++nt) {
        const float* prow = P + ((size_t)b * C_ + cb + nt * 16 + n16) * R_ + quad * 8;
        float4 p0 = *reinterpret_cast<const float4*>(prow);
        float4 p1 = *reinterpret_cast<const float4*>(prow + 4);
        union { bf16x8 v8; unsigned u[4]; } bf;
        bf.u[0] = pkbf(p0.x * ga0.x, p0.y * ga0.y);
        bf.u[1] = pkbf(p0.z * ga0.z, p0.w * ga0.w);
        bf.u[2] = pkbf(p1.x * ga1.x, p1.y * ga1.y);
        bf.u[3] = pkbf(p1.z * ga1.z, p1.w * ga1.w);
        acc[nt] = __builtin_amdgcn_mfma_f32_16x16x32_bf16(af0, bf.v8, acc[nt], 0, 0, 0);
        float4 q0 = *reinterpret_cast<const float4*>(prow + 32);
        float4 q1 = *reinterpret_cast<const float4*>(prow + 36);
        bf.u[0] = pkbf(q0.x * gb0.x, q0.y * gb0.y);
        bf.u[1] = pkbf(q0.z * gb0.z, q0.w * gb0.w);
        bf.u[2] = pkbf(q1.x * gb1.x, q1.y * gb1.y);
        bf.u[3] = pkbf(q1.z * gb1.z, q1.w * gb1.w);
        acc[nt] = __builtin_amdgcn_mfma_f32_16x16x32_bf16(af1, bf.v8, acc[nt], 0, 0, 0);
    }

    // vals[nt][e] at (l = l0 + 4*quad + e, c = cb + 16*nt + n16)
    float ab[4];
#pragma unroll
    for (int e = 0; e < 4; ++e) ab[e] = alpha * bu[l0 + quad * 4 + e];
    const float* xrow = x + ((size_t)b * L_ + l0 + quad * 4) * C_ + cb + n16;
    float vals[4][4];
#pragma unroll
    for (int nt = 0; nt < 4; ++nt)
#pragma unroll
        for (int e = 0; e < 4; ++e)
            vals[nt][e] = xrow[(size_t)e * C_ + nt * 16] + alpha * acc[nt][e] + ab[e];

    // LN over c: 16-lane shfl tree (4 hops vs old 6) + 8-wave LDS combine
    __shared__ float2 red[TL][8];
    __shared__ float2 mv[TL];
#pragma unroll
    for (int e = 0; e < 4; ++e) {
        float s  = vals[0][e] + vals[1][e] + vals[2][e] + vals[3][e];
        float s2 = vals[0][e] * vals[0][e] + vals[1][e] * vals[1][e]
                 + vals[2][e] * vals[2][e] + vals[3][e] * vals[3][e];
#pragma unroll
        for (int off = 1; off < 16; off <<= 1) {
            s  += __shfl_xor(s, off, 64);
            s2 += __shfl_xor(s2, off, 64);
        }
        if (n16 == 0) red[quad * 4 + e][wv] = make_float2(s, s2);
    }
    __syncthreads();
    if (tid < TL) {
        float s = 0.f, s2 = 0.f;
#pragma unroll
        for (int w = 0; w < 8; ++w) { s += red[tid][w].x; s2 += red[tid][w].y; }
        const float mean = s * (1.f / C_);
        const float var  = s2 * (1.f / C_) - mean * mean;
        mv[tid] = make_float2(mean, rsqrtf(var + 1e-5f));
    }
    __syncthreads();
    float* orow = out + ((size_t)b * L_ + l0 + quad * 4) * C_ + cb + n16;
#pragma unroll
    for (int nt = 0; nt < 4; ++nt) {
        const int c = cb + nt * 16 + n16;
        const float gm = gamma[c], bt = beta[c];
#pragma unroll
        for (int e = 0; e < 4; ++e) {
            const float2 m = mv[quad * 4 + e];
            orow[(size_t)e * C_ + nt * 16] = (vals[nt][e] - m.x) * m.y * gm + bt;
        }
    }
}

// ---------------------------------------------------------------------------
extern "C" void kernel_launch(void* const* d_in, const int* in_sizes, int n_in,
                              void* d_out, int out_size, void* d_ws, size_t ws_size,
                              hipStream_t stream) {
    const float* x     = (const float*)d_in[0];
    const float* Wd    = (const float*)d_in[1];
    const float* bd    = (const float*)d_in[2];
    const float* Wq    = (const float*)d_in[3];
    const float* Wk    = (const float*)d_in[4];
    const float* Wv    = (const float*)d_in[5];
    const float* Wg    = (const float*)d_in[6];
    const float* bg    = (const float*)d_in[7];
    const float* Wu    = (const float*)d_in[8];
    const float* bu    = (const float*)d_in[9];
    const float* gamma = (const float*)d_in[10];
    const float* beta  = (const float*)d_in[11];
    const float* alpha = (const float*)d_in[12];
    float* out = (float*)d_out;

    char* ws = (char*)d_ws;
    __hip_bfloat16* Wt  = (__hip_bfloat16*)ws;                     // 256 KB
    __hip_bfloat16* Wub = (__hip_bfloat16*)(ws + (256 << 10));     // 256 KB
    float* hl = (float*)(ws + (512 << 10));                        // 8 MB (B,C,R)
    float* P  = (float*)(ws + (512 << 10) + (8 << 20));            // 8 MB (B,C,R)
    float* G  = (float*)(ws + (512 << 10) + (16 << 20));           // 16 KB (B,R)

    k_cast<<<dim3((2 * R_ * L_) / 256), 256, 0, stream>>>(Wd, Wu, Wt, Wub);
    hipMemsetAsync(hl, 0, (size_t)B_ * C_ * R_ * sizeof(float), stream);
    hipMemsetAsync(G, 0, B_ * R_ * sizeof(float), stream);
    k_hlow_mfma<<<dim3(C_ / BM, NSL, B_), 256, 0, stream>>>(x, Wt, hl);
    k_qkvg<<<dim3(C_ / 32, B_), 256, 0, stream>>>(hl, bd, Wq, Wk, Wv, Wg, bg, P, G);
    k_out<<<dim3(L_ / TL, B_), 512, 0, stream>>>(x, P, G, Wub, bu, gamma, beta, alpha, out);
}

// Round 2
// 696.310 us; speedup vs baseline: 1.1556x; 1.0644x over previous
//
#include <hip/hip_runtime.h>
#include <hip/hip_bf16.h>
#include <math.h>

#define B_ 64
#define L_ 2048
#define C_ 512
#define R_ 64
#define TL 16

#define BM 128     // c-tile per block in k_hlow (4 waves x 32 c)
#define BK 32      // l-chunk (one MFMA K)
#define LDK 36     // padded LDS row length in floats (rows step 4 banks)
#define NSL 4      // L-slices in k_hlow (1024 blocks; atomic RMW halved vs 8)
#define LSL (L_ / NSL)
#define LDV 516    // k_out LDS row pad: 516 mod 32 = 4 -> 2-way max, 16B-aligned rows

typedef __attribute__((ext_vector_type(8))) short bf16x8;  // 8 bf16 (4 VGPRs)
typedef __attribute__((ext_vector_type(4))) float f32x4;   // MFMA acc

static __device__ __forceinline__ unsigned pkbf(float a, float b) {
    __hip_bfloat162 t = __float22bfloat162_rn(make_float2(a, b));
    union { __hip_bfloat162 h; unsigned u; } cv;
    cv.h = t;
    return cv.u;
}

// ---------------------------------------------------------------------------
// Cast Wd (R,L), Wu (L,R), Wq/Wk/Wv/Wg (R,R) fp32 -> bf16, same layouts.
// All row-major with contiguous K = exactly the MFMA fragment layouts.
// ---------------------------------------------------------------------------
__global__ void k_cast(const float* __restrict__ Wd,
                       const float* __restrict__ Wu,
                       const float* __restrict__ Wq,
                       const float* __restrict__ Wk,
                       const float* __restrict__ Wv,
                       const float* __restrict__ Wg,
                       __hip_bfloat16* __restrict__ Wt,
                       __hip_bfloat16* __restrict__ Wub,
                       __hip_bfloat16* __restrict__ Wqb,
                       __hip_bfloat16* __restrict__ Wkb,
                       __hip_bfloat16* __restrict__ Wvb,
                       __hip_bfloat16* __restrict__ Wgb) {
    const int i  = blockIdx.x * 256 + threadIdx.x;   // grid = (2*R*L + 4*R*R)/256
    const int RL = R_ * L_;
    if (i < RL)          Wt[i]       = __float2bfloat16(Wd[i]);
    else if (i < 2 * RL) Wub[i - RL] = __float2bfloat16(Wu[i - RL]);
    else {
        const int idx = i - 2 * RL;
        const int mat = idx >> 12;          // R_*R_ = 4096
        const int off = idx & 4095;
        const float* src = mat == 0 ? Wq : mat == 1 ? Wk : mat == 2 ? Wv : Wg;
        __hip_bfloat16* dst = mat == 0 ? Wqb : mat == 1 ? Wkb : mat == 2 ? Wvb : Wgb;
        dst[off] = __float2bfloat16(src[off]);
    }
}

// ---------------------------------------------------------------------------
// bias4[mat][s] = sum_r bd[r] * W_mat[s][r]  (+ bg[s] for the gate matrix):
// folds the (h_low + bd) bias through the q/k/v/g matmuls exactly, so
// k_qkvg's MFMA operates on hl alone. fp32-exact.
// ---------------------------------------------------------------------------
__global__ void k_bias(const float* __restrict__ bd,
                       const float* __restrict__ bg,
                       const float* __restrict__ Wq,
                       const float* __restrict__ Wk,
                       const float* __restrict__ Wv,
                       const float* __restrict__ Wg,
                       float* __restrict__ bias4) {
    const int t = threadIdx.x;               // 256 = 4 mats x 64 s
    const int mat = t >> 6, s = t & 63;
    const float* W = mat == 0 ? Wq : mat == 1 ? Wk : mat == 2 ? Wv : Wg;
    float acc = (mat == 3) ? bg[s] : 0.f;
#pragma unroll 8
    for (int r = 0; r < R_; ++r) acc += bd[r] * W[s * R_ + r];
    bias4[mat * R_ + s] = acc;
}

// ---------------------------------------------------------------------------
// Kernel A (MFMA): hl[b][c][r] += sum_l x[b][l][c] * Wd[r][l]   ((B,C,R))
// Pipelined: next chunk's x + Wd frags are issued right after the second
// barrier, so their latency hides under this chunk's frag-assembly + 8 MFMAs
// + the next barrier (old code issued loads immediately before the barrier
// that consumed them -> latency exposed every K-step).
// ---------------------------------------------------------------------------
__device__ __forceinline__ void hlow_step(
        float (&v)[16], bf16x8 (&bfr)[4], bf16x8 (&bfn)[4],
        const float* __restrict__ xptr, const __hip_bfloat16* __restrict__ wbase,
        int kc_next, bool has_next,
        float (*xs)[LDK], int cs, int lh, int wv, int quad, int mrow,
        f32x4 (&acc)[2][4]) {
    __syncthreads();                          // xs free (readers of prev done)
#pragma unroll
    for (int i = 0; i < 16; i += 4)
        *reinterpret_cast<float4*>(&xs[cs][lh + i]) =
            make_float4(v[i], v[i + 1], v[i + 2], v[i + 3]);
    __syncthreads();                          // xs ready
    if (has_next) {                           // prefetch next chunk (WAR on v ok)
#pragma unroll
        for (int i = 0; i < 16; ++i) v[i] = xptr[(size_t)(kc_next + i) * C_];
#pragma unroll
        for (int nt = 0; nt < 4; ++nt)
            bfn[nt] = *reinterpret_cast<const bf16x8*>(
                wbase + (size_t)(nt * 16 + mrow) * L_ + kc_next);
    }
#pragma unroll
    for (int mt = 0; mt < 2; ++mt) {
        const float* ap = &xs[wv * 32 + mt * 16 + mrow][quad * 8];
        float4 lo = *reinterpret_cast<const float4*>(ap);
        float4 hi = *reinterpret_cast<const float4*>(ap + 4);
        union { bf16x8 v8; unsigned u[4]; } af;
        af.u[0] = pkbf(lo.x, lo.y);
        af.u[1] = pkbf(lo.z, lo.w);
        af.u[2] = pkbf(hi.x, hi.y);
        af.u[3] = pkbf(hi.z, hi.w);
#pragma unroll
        for (int nt = 0; nt < 4; ++nt)
            acc[mt][nt] = __builtin_amdgcn_mfma_f32_16x16x32_bf16(
                af.v8, bfr[nt], acc[mt][nt], 0, 0, 0);
    }
}

__global__ __launch_bounds__(256) void k_hlow_mfma(
        const float* __restrict__ x,
        const __hip_bfloat16* __restrict__ Wt,
        float* __restrict__ hl) {
    __shared__ float xs[BM][LDK];            // 18432 B

    const int tid  = threadIdx.x;
    const int lane = tid & 63;
    const int wv   = tid >> 6;
    const int quad = lane >> 4;
    const int mrow = lane & 15;

    const int c0     = blockIdx.x * BM;
    const int l_base = blockIdx.y * LSL;
    const int b      = blockIdx.z;

    const int cs = tid & 127;
    const int lh = (tid >> 7) * 16;

    f32x4 acc[2][4];
#pragma unroll
    for (int mt = 0; mt < 2; ++mt)
#pragma unroll
        for (int nt = 0; nt < 4; ++nt)
#pragma unroll
            for (int e = 0; e < 4; ++e) acc[mt][nt][e] = 0.f;

    const float* xptr = x + ((size_t)b * L_ + l_base + lh) * C_ + c0 + cs;
    const __hip_bfloat16* wbase = Wt + l_base + quad * 8;

    float v[16];
    bf16x8 bf0[4], bf1[4];
#pragma unroll
    for (int i = 0; i < 16; ++i) v[i] = xptr[(size_t)i * C_];
#pragma unroll
    for (int nt = 0; nt < 4; ++nt)
        bf0[nt] = *reinterpret_cast<const bf16x8*>(
            wbase + (size_t)(nt * 16 + mrow) * L_);

    // LSL/BK = 16 steps, unrolled x2 for static double-buffer reg selection
    for (int kc = 0; kc < LSL; kc += 2 * BK) {
        hlow_step(v, bf0, bf1, xptr, wbase, kc + BK, true,
                  xs, cs, lh, wv, quad, mrow, acc);
        hlow_step(v, bf1, bf0, xptr, wbase, kc + 2 * BK, kc + 2 * BK < LSL,
                  xs, cs, lh, wv, quad, mrow, acc);
    }

    // C/D: col(n=r)=lane&15, row(m=c)=quad*4+e  -> hl[b][c][r]
#pragma unroll
    for (int mt = 0; mt < 2; ++mt)
#pragma unroll
        for (int nt = 0; nt < 4; ++nt) {
            const int rg = nt * 16 + mrow;
            const int cg = c0 + wv * 32 + mt * 16 + quad * 4;
#pragma unroll
            for (int e = 0; e < 4; ++e)
                atomicAdd(&hl[((size_t)b * C_ + cg + e) * R_ + rg],
                          acc[mt][nt][e]);
        }
}

// ---------------------------------------------------------------------------
// Kernel B (MFMA now): Q/K/V/G projections as 4 GEMMs (M=c, N=s, K=r=64).
// A = hl (B,C,R): r-contiguous = A-frag layout directly (2 float4 + pkbf).
// B = W (s,r) bf16 row-major: r-contiguous = B-frag layout directly.
// Zero LDS for the matmul; bias folded via bias4 = bd@W^T (+bg for gate).
// Replaces 2048 scalar FMAs + 512 vector loads/thread with 32 MFMAs/wave.
// Wave w of 4 owns c-tile [c0+16w, +16); grid (C/64, B) = 512 blocks.
// ---------------------------------------------------------------------------
__global__ __launch_bounds__(256) void k_qkvg(
        const float* __restrict__ hl,
        const __hip_bfloat16* __restrict__ Wqb,
        const __hip_bfloat16* __restrict__ Wkb,
        const __hip_bfloat16* __restrict__ Wvb,
        const __hip_bfloat16* __restrict__ Wgb,
        const float* __restrict__ bias4,
        float* __restrict__ P,
        float* __restrict__ G) {
    const int tid  = threadIdx.x;
    const int lane = tid & 63;
    const int w    = tid >> 6;
    const int n16  = lane & 15;
    const int quad = lane >> 4;
    const int b    = blockIdx.y;
    const int c0   = blockIdx.x * 64 + w * 16;

    // A-frags: rows c0+n16; af0 covers r 0..31, af1 r 32..63
    const float* hrow = hl + ((size_t)b * C_ + c0 + n16) * R_ + quad * 8;
    float4 a0 = *reinterpret_cast<const float4*>(hrow);
    float4 a1 = *reinterpret_cast<const float4*>(hrow + 4);
    float4 a2 = *reinterpret_cast<const float4*>(hrow + 32);
    float4 a3 = *reinterpret_cast<const float4*>(hrow + 36);
    union { bf16x8 v8; unsigned u[4]; } af0, af1;
    af0.u[0] = pkbf(a0.x, a0.y); af0.u[1] = pkbf(a0.z, a0.w);
    af0.u[2] = pkbf(a1.x, a1.y); af0.u[3] = pkbf(a1.z, a1.w);
    af1.u[0] = pkbf(a2.x, a2.y); af1.u[1] = pkbf(a2.z, a2.w);
    af1.u[2] = pkbf(a3.x, a3.y); af1.u[3] = pkbf(a3.z, a3.w);

    const __hip_bfloat16* Ws[4] = {Wqb, Wkb, Wvb, Wgb};
    f32x4 acc[4][4];                       // [mat][nt]
#pragma unroll
    for (int m = 0; m < 4; ++m)
#pragma unroll
        for (int nt = 0; nt < 4; ++nt)
#pragma unroll
            for (int e = 0; e < 4; ++e) acc[m][nt][e] = 0.f;

#pragma unroll
    for (int m = 0; m < 4; ++m) {
        const __hip_bfloat16* wb = Ws[m];
#pragma unroll
        for (int nt = 0; nt < 4; ++nt) {
            const __hip_bfloat16* brow = wb + (size_t)(nt * 16 + n16) * R_ + quad * 8;
            bf16x8 bfr0 = *reinterpret_cast<const bf16x8*>(brow);
            bf16x8 bfr1 = *reinterpret_cast<const bf16x8*>(brow + 32);
            acc[m][nt] = __builtin_amdgcn_mfma_f32_16x16x32_bf16(af0.v8, bfr0, acc[m][nt], 0, 0, 0);
            acc[m][nt] = __builtin_amdgcn_mfma_f32_16x16x32_bf16(af1.v8, bfr1, acc[m][nt], 0, 0, 0);
        }
    }

    // biases, indexed s = nt*16+n16 (same for all e)
    float bia[4][4];
#pragma unroll
    for (int m = 0; m < 4; ++m)
#pragma unroll
        for (int nt = 0; nt < 4; ++nt) bia[m][nt] = bias4[m * R_ + nt * 16 + n16];

    // D: col(lane&15)=s, row(quad*4+e)=c. Norms: reduce q^2,k^2 over the 16
    // n16-lanes (covers all 64 s after summing nt) -> 4 hops per e.
    float inq[4], ink[4];
#pragma unroll
    for (int e = 0; e < 4; ++e) {
        float tq = 0.f, tk = 0.f;
#pragma unroll
        for (int nt = 0; nt < 4; ++nt) {
            const float q = acc[0][nt][e] + bia[0][nt];
            const float k = acc[1][nt][e] + bia[1][nt];
            tq += q * q; tk += k * k;
        }
#pragma unroll
        for (int off = 1; off < 16; off <<= 1) {
            tq += __shfl_xor(tq, off, 64);
            tk += __shfl_xor(tk, off, 64);
        }
        inq[e] = 1.f / fmaxf(sqrtf(tq), 1e-12f);
        ink[e] = 1.f / fmaxf(sqrtf(tk), 1e-12f);
    }

    // P store (fp32, (B,C,R): feeds k_out B-frags) + G partial
    float gs[4] = {0.f, 0.f, 0.f, 0.f};
    const int crow = c0 + quad * 4;
#pragma unroll
    for (int nt = 0; nt < 4; ++nt) {
        const int s = nt * 16 + n16;
        float* pp = P + ((size_t)b * C_ + crow) * R_ + s;
#pragma unroll
        for (int e = 0; e < 4; ++e) {
            const float q = (acc[0][nt][e] + bia[0][nt]) * inq[e];
            const float k = (acc[1][nt][e] + bia[1][nt]) * ink[e];
            const float v = acc[2][nt][e] + bia[2][nt];
            const float g = acc[3][nt][e] + bia[3][nt];
            const float gate = 1.f / (1.f + expf(-g));
            pp[(size_t)e * R_] = q * gate;
            gs[nt] += k * v;
        }
    }
    // reduce gs over the wave's 16 c (lanes i, i^16, i^32, i^48), then block
#pragma unroll
    for (int nt = 0; nt < 4; ++nt) {
        gs[nt] += __shfl_xor(gs[nt], 16, 64);
        gs[nt] += __shfl_xor(gs[nt], 32, 64);
    }
    __shared__ float gred[4][R_];
    if (lane < 16)
#pragma unroll
        for (int nt = 0; nt < 4; ++nt) gred[w][nt * 16 + lane] = gs[nt];
    __syncthreads();
    if (tid < R_)
        atomicAdd(&G[b * R_ + tid],
                  gred[0][tid] + gred[1][tid] + gred[2][tid] + gred[3][tid]);
}

// ---------------------------------------------------------------------------
// Kernel C (MFMA): out = LN_c( x + alpha*((P.G) @ Wu^T + bu) )*gamma + beta
// Phase 1 (MFMA) unchanged; acc staged through LDS vs[16][516] (row pad ≡ 4
// mod 32 banks -> ≤2-way conflicts). Phase 2 remaps threads to (l = tid&15,
// 16 contiguous c): x loads, out stores, gamma/beta all dwordx4; LN reduce =
// 2 shfl hops + 16x8 LDS combine. Targets the latency-bound profile
// (VALU 18%, HBM 24%, MFMA 1.5% at 224 µs vs a 69 µs byte floor).
// ---------------------------------------------------------------------------
__global__ __launch_bounds__(512) void k_out(const float* __restrict__ x,
                                             const float* __restrict__ P,
                                             const float* __restrict__ G,
                                             const __hip_bfloat16* __restrict__ Wub,
                                             const float* __restrict__ bu,
                                             const float* __restrict__ gamma,
                                             const float* __restrict__ beta,
                                             const float* __restrict__ alpha_p,
                                             float* __restrict__ out) {
    __shared__ float vs[TL][LDV];          // 33024 B
    __shared__ float2 red[TL][8];
    __shared__ float2 mv[TL];

    const int tid  = threadIdx.x;
    const int lane = tid & 63;
    const int wv   = tid >> 6;             // 0..7
    const int n16  = lane & 15;
    const int quad = lane >> 4;
    const int b    = blockIdx.y;
    const int l0   = blockIdx.x * TL;
    const float alpha = alpha_p[0];

    // ---- phase 1: MFMA (A = Wu bf16, B = P*G bf16)
    const __hip_bfloat16* wrow = Wub + (size_t)(l0 + n16) * R_ + quad * 8;
    const bf16x8 af0 = *reinterpret_cast<const bf16x8*>(wrow);
    const bf16x8 af1 = *reinterpret_cast<const bf16x8*>(wrow + 32);

    const float* gp = G + b * R_ + quad * 8;
    const float4 ga0 = *reinterpret_cast<const float4*>(gp);
    const float4 ga1 = *reinterpret_cast<const float4*>(gp + 4);
    const float4 gb0 = *reinterpret_cast<const float4*>(gp + 32);
    const float4 gb1 = *reinterpret_cast<const float4*>(gp + 36);

    f32x4 acc[4];
#pragma unroll
    for (int nt = 0; nt < 4; ++nt)
#pragma unroll
        for (int e = 0; e < 4; ++e) acc[nt][e] = 0.f;

    const int cb = wv * 64;
#pragma unroll
    for (int nt = 0; nt < 4; ++nt) {
        const float* prow = P + ((size_t)b * C_ + cb + nt * 16 + n16) * R_ + quad * 8;
        float4 p0 = *reinterpret_cast<const float4*>(prow);
        float4 p1 = *reinterpret_cast<const float4*>(prow + 4);
        union { bf16x8 v8; unsigned u[4]; } bf;
        bf.u[0] = pkbf(p0.x * ga0.x, p0.y * ga0.y);
        bf.u[1] = pkbf(p0.z * ga0.z, p0.w * ga0.w);
        bf.u[2] = pkbf(p1.x * ga1.x, p1.y * ga1.y);
        bf.u[3] = pkbf(p1.z * ga1.z, p1.w * ga1.w);
        acc[nt] = __builtin_amdgcn_mfma_f32_16x16x32_bf16(af0, bf.v8, acc[nt], 0, 0, 0);
        float4 q0 = *reinterpret_cast<const float4*>(prow + 32);
        float4 q1 = *reinterpret_cast<const float4*>(prow + 36);
        bf.u[0] = pkbf(q0.x * gb0.x, q0.y * gb0.y);
        bf.u[1] = pkbf(q0.z * gb0.z, q0.w * gb0.w);
        bf.u[2] = pkbf(q1.x * gb1.x, q1.y * gb1.y);
        bf.u[3] = pkbf(q1.z * gb1.z, q1.w * gb1.w);
        acc[nt] = __builtin_amdgcn_mfma_f32_16x16x32_bf16(af1, bf.v8, acc[nt], 0, 0, 0);
    }

    // ---- phase-2 mapping + early x loads (independent of LDS stage)
    const int lrow = tid & 15;
    const int cseg = tid >> 4;             // 0..31
    const int c0r  = cseg * 16;
    const int l    = l0 + lrow;
    const float* xr = x + ((size_t)b * L_ + l) * C_ + c0r;
    float xv[16];
#pragma unroll
    for (int j = 0; j < 4; ++j) {
        float4 t = *reinterpret_cast<const float4*>(xr + 4 * j);
        xv[4 * j + 0] = t.x; xv[4 * j + 1] = t.y;
        xv[4 * j + 2] = t.z; xv[4 * j + 3] = t.w;
    }

    // ---- stage acc -> LDS (D layout: l = quad*4+e, c = cb + nt*16 + n16)
#pragma unroll
    for (int nt = 0; nt < 4; ++nt)
#pragma unroll
        for (int e = 0; e < 4; ++e)
            vs[quad * 4 + e][cb + nt * 16 + n16] = acc[nt][e];
    __syncthreads();

    // ---- phase 2: row-contiguous vals
    const float abu = alpha * bu[l];
    float vals[16];
#pragma unroll
    for (int j = 0; j < 4; ++j) {
        float4 t = *reinterpret_cast<const float4*>(&vs[lrow][c0r + 4 * j]);
        vals[4 * j + 0] = xv[4 * j + 0] + alpha * t.x + abu;
        vals[4 * j + 1] = xv[4 * j + 1] + alpha * t.y + abu;
        vals[4 * j + 2] = xv[4 * j + 2] + alpha * t.z + abu;
        vals[4 * j + 3] = xv[4 * j + 3] + alpha * t.w + abu;
    }

    // LN: lanes sharing lrow within a wave are {i, i^16, i^32, i^48}
    float s = 0.f, s2 = 0.f;
#pragma unroll
    for (int i = 0; i < 16; ++i) { s += vals[i]; s2 += vals[i] * vals[i]; }
    s  += __shfl_xor(s, 16, 64);  s2 += __shfl_xor(s2, 16, 64);
    s  += __shfl_xor(s, 32, 64);  s2 += __shfl_xor(s2, 32, 64);
    if (lane < 16) red[lane][wv] = make_float2(s, s2);
    __syncthreads();
    if (tid < TL) {
        float t = 0.f, t2 = 0.f;
#pragma unroll
        for (int w = 0; w < 8; ++w) { t += red[tid][w].x; t2 += red[tid][w].y; }
        const float mean = t * (1.f / C_);
        const float var  = t2 * (1.f / C_) - mean * mean;
        mv[tid] = make_float2(mean, rsqrtf(var + 1e-5f));
    }
    __syncthreads();
    const float2 m = mv[lrow];
    float* orow = out + ((size_t)b * L_ + l) * C_ + c0r;
#pragma unroll
    for (int j = 0; j < 4; ++j) {
        float4 gm = *reinterpret_cast<const float4*>(gamma + c0r + 4 * j);
        float4 bt = *reinterpret_cast<const float4*>(beta + c0r + 4 * j);
        float4 o;
        o.x = (vals[4 * j + 0] - m.x) * m.y * gm.x + bt.x;
        o.y = (vals[4 * j + 1] - m.x) * m.y * gm.y + bt.y;
        o.z = (vals[4 * j + 2] - m.x) * m.y * gm.z + bt.z;
        o.w = (vals[4 * j + 3] - m.x) * m.y * gm.w + bt.w;
        *reinterpret_cast<float4*>(orow + 4 * j) = o;
    }
}

// ---------------------------------------------------------------------------
extern "C" void kernel_launch(void* const* d_in, const int* in_sizes, int n_in,
                              void* d_out, int out_size, void* d_ws, size_t ws_size,
                              hipStream_t stream) {
    const float* x     = (const float*)d_in[0];
    const float* Wd    = (const float*)d_in[1];
    const float* bd    = (const float*)d_in[2];
    const float* Wq    = (const float*)d_in[3];
    const float* Wk    = (const float*)d_in[4];
    const float* Wv    = (const float*)d_in[5];
    const float* Wg    = (const float*)d_in[6];
    const float* bg    = (const float*)d_in[7];
    const float* Wu    = (const float*)d_in[8];
    const float* bu    = (const float*)d_in[9];
    const float* gamma = (const float*)d_in[10];
    const float* beta  = (const float*)d_in[11];
    const float* alpha = (const float*)d_in[12];
    float* out = (float*)d_out;

    char* ws = (char*)d_ws;
    __hip_bfloat16* Wt  = (__hip_bfloat16*)ws;                     // 256 KB
    __hip_bfloat16* Wub = (__hip_bfloat16*)(ws + (256 << 10));     // 256 KB
    __hip_bfloat16* Wqb = (__hip_bfloat16*)(ws + (512 << 10));     // 8 KB
    __hip_bfloat16* Wkb = (__hip_bfloat16*)(ws + (520 << 10));     // 8 KB
    __hip_bfloat16* Wvb = (__hip_bfloat16*)(ws + (528 << 10));     // 8 KB
    __hip_bfloat16* Wgb = (__hip_bfloat16*)(ws + (536 << 10));     // 8 KB
    float* bias4        = (float*)(ws + (544 << 10));              // 1 KB
    float* hl           = (float*)(ws + (576 << 10));              // 8 MB (B,C,R)
    float* P            = (float*)(ws + (576 << 10) + (8 << 20));  // 8 MB (B,C,R)
    float* G            = (float*)(ws + (576 << 10) + (16 << 20)); // 16 KB

    k_cast<<<dim3((2 * R_ * L_ + 4 * R_ * R_) / 256), 256, 0, stream>>>(
        Wd, Wu, Wq, Wk, Wv, Wg, Wt, Wub, Wqb, Wkb, Wvb, Wgb);
    k_bias<<<1, 256, 0, stream>>>(bd, bg, Wq, Wk, Wv, Wg, bias4);
    hipMemsetAsync(hl, 0, (size_t)B_ * C_ * R_ * sizeof(float), stream);
    hipMemsetAsync(G, 0, B_ * R_ * sizeof(float), stream);
    k_hlow_mfma<<<dim3(C_ / BM, NSL, B_), 256, 0, stream>>>(x, Wt, hl);
    k_qkvg<<<dim3(C_ / 64, B_), 256, 0, stream>>>(hl, Wqb, Wkb, Wvb, Wgb,
                                                  bias4, P, G);
    k_out<<<dim3(L_ / TL, B_), 512, 0, stream>>>(x, P, G, Wub, bu, gamma, beta,
                                                 alpha, out);
}